// Round 15
// baseline (1222.759 us; speedup 1.0000x reference)
//
#include <hip/hip_runtime.h>
#include <stdint.h>
#include <limits.h>

// ---------- exact-rounding helpers (match numpy op order; used in selection kernels) ----------
__device__ inline float mul_rn(float a, float b){ float r; asm("v_mul_f32 %0, %1, %2" : "=v"(r) : "v"(a), "v"(b)); return r; }
__device__ inline float add_rn(float a, float b){ float r; asm("v_add_f32 %0, %1, %2" : "=v"(r) : "v"(a), "v"(b)); return r; }
__device__ inline float sub_rn(float a, float b){ float r; asm("v_sub_f32 %0, %1, %2" : "=v"(r) : "v"(a), "v"(b)); return r; }

typedef uint16_t u16x8 __attribute__((ext_vector_type(8)));
typedef float    f32x2 __attribute__((ext_vector_type(2)));
typedef short    bf16x8 __attribute__((ext_vector_type(8)));
typedef float    fx4 __attribute__((ext_vector_type(4)));

__device__ inline float bf2f(uint16_t u){ return __uint_as_float(((uint32_t)u) << 16); }
__device__ inline uint16_t f2bf(float f){
    uint32_t u = __float_as_uint(f);
    u += 0x7fffu + ((u >> 16) & 1u);   // RNE
    return (uint16_t)(u >> 16);
}
__device__ inline unsigned fkey(float f){
    unsigned u = __float_as_uint(f);
    return (u & 0x80000000u) ? ~u : (u | 0x80000000u);
}
__device__ inline float funkey(unsigned k){
    unsigned u = (k & 0x80000000u) ? (k ^ 0x80000000u) : ~k;
    return __uint_as_float(u);
}

// full-wave u32 max via DPP builtins (compiler inserts hazard waits). Valid in lane 63.
__device__ inline unsigned dpp_umax_wave(unsigned v){
    unsigned t;
    t = (unsigned)__builtin_amdgcn_update_dpp((int)v, (int)v, 0x111, 0xf, 0xf, false); v = v > t ? v : t;
    t = (unsigned)__builtin_amdgcn_update_dpp((int)v, (int)v, 0x112, 0xf, 0xf, false); v = v > t ? v : t;
    t = (unsigned)__builtin_amdgcn_update_dpp((int)v, (int)v, 0x114, 0xf, 0xf, false); v = v > t ? v : t;
    t = (unsigned)__builtin_amdgcn_update_dpp((int)v, (int)v, 0x118, 0xf, 0xf, false); v = v > t ? v : t;
    t = (unsigned)__builtin_amdgcn_update_dpp((int)v, (int)v, 0x142, 0xf, 0xf, false); v = v > t ? v : t;
    t = (unsigned)__builtin_amdgcn_update_dpp((int)v, (int)v, 0x143, 0xf, 0xf, false); v = v > t ? v : t;
    return v;
}

#define NPTS   8192
#define NBATCH 16
#define NPOINT 1024
#define NSAMP  32
#define LCOLS  32768          // NPOINT*NSAMP
#define NTOT   524288.0f      // 16*32768
#define NBUCK  32

// ---------- workspace layout (bytes) ----------
#define OFF_FPS   0u               // 16*1024*4 = 65536
#define OFF_GIDX  65536u           // 16*1024*32*4 = 2097152
#define OFF_SSC   2162688u         // 3 layers * 32 buckets * 256 f32 = 98304
#define OFF_MM    2263040u         // mmax 2048 u32 ; mmin 2048 u32 = 16384
#define OFF_WPK0  2279424u         // 6144 u16 = 12288 (layer0, K=96 permuted)
#define OFF_WPK1  2291712u         // 4096 u16 = 8192
#define OFF_WPK2  2299904u         // 8192 u16 = 16384 (end 2316288)
#define OFF_T0    4194304u         // 67108864 (raw conv0 out, bf16)
#define OFF_PTST  138412032u       // 16777216 (end 155189248)

// ---------- 1) FUSED (512 thr/block): fps (0..15) + pts transpose (16..2063) + prep (2064..2079) ----------
__global__ __launch_bounds__(512) void fps_fused_kernel(const float* __restrict__ xyz,
        int* __restrict__ fps_idx, float* __restrict__ out_xyz,
        const float* __restrict__ pts, uint16_t* __restrict__ ptsT,
        const float* __restrict__ w0, const float* __restrict__ w1, const float* __restrict__ w2,
        uint16_t* __restrict__ wpk0, uint16_t* __restrict__ wpk1, uint16_t* __restrict__ wpk2){
#pragma clang fp contract(off)
    __shared__ __align__(16) float smem[33824];   // sxyz4 32768 + wslots 32 + sidx 1024
    const int bid = blockIdx.x, tid = threadIdx.x;

    if (bid >= 2064){                      // ---- prep path: pack weights for MFMA ----
        int t = (bid - 2064) * 512 + tid;  // 0..8191
        if (t < 64*96){                    // layer0: channel-permuted K=96 (pts 0..63, xyz 64..66, pad)
            int o = t / 96, cp = t % 96;
            uint16_t v = 0;
            if (cp < 64)      v = f2bf(w0[o*67 + (cp + 3)]);   // pts channel
            else if (cp < 67) v = f2bf(w0[o*67 + (cp - 64)]);  // xyz channel
            wpk0[((cp>>3)*64 + o)*8 + (cp&7)] = v;
        }
        if (t < 64*64){ int o = t >> 6, c = t & 63; wpk1[((c>>3)*64  + o)*8 + (c&7)] = f2bf(w1[t]); }
        if (t < 128*64){ int o = t >> 6, c = t & 63; wpk2[((c>>3)*128 + o)*8 + (c&7)] = f2bf(w2[t]); }
        return;
    }
    if (bid >= 16){                        // ---- transpose path: (B,64,N)f32 -> (B,N,64)bf16 ----
        float (*tile)[65] = (float(*)[65])smem;
        const int tb = bid - 16;
        const int bt = tb >> 7, n0 = (tb & 127) << 6;
        const int tn = tid & 63, tg = tid >> 6;             // tg 0..7, 8 c's each
        const float* src = pts + (size_t)bt * 64 * NPTS + n0;
#pragma unroll
        for (int i = 0; i < 8; i++){ int c = tg*8 + i; tile[c][tn] = src[(size_t)c * NPTS + tn]; }
        __syncthreads();
        uint16_t* dst = ptsT + ((size_t)bt * NPTS + n0) * 64;
#pragma unroll
        for (int i = 0; i < 8; i++){ int n = tg*8 + i; dst[(size_t)n * 64 + tn] = f2bf(tile[tn][n]); }
        return;
    }

    // ---- fps path: 512 threads (2 waves/SIMD), 16 points/thread, EXACT numpy-order arithmetic ----
    float* sxyz = smem;
    float4* sxyz4 = (float4*)smem;
    unsigned long long* wslots = (unsigned long long*)(smem + 32768);   // [2*8]
    int* sidx = (int*)(smem + 32800);                                   // [1024]
    const int b = bid;
    const float* px = xyz + (size_t)b * 3 * NPTS;
    for (int i = tid; i < NPTS; i += 512)
        sxyz4[i] = float4{px[i], px[NPTS + i], px[2*NPTS + i], 0.f};
    __syncthreads();

    const int p0 = tid << 4;
    const float4* rp = sxyz4 + p0;
    f32x2 X2[8], Y2[8], Z2[8], M2[8];
#pragma unroll
    for (int j = 0; j < 8; j++){
        float4 qa = rp[2*j], qb = rp[2*j + 1];
        X2[j] = f32x2{qa.x, qb.x};
        Y2[j] = f32x2{qa.y, qb.y};
        Z2[j] = f32x2{qa.z, qb.z};
        M2[j] = f32x2{1e10f, 1e10f};
    }
    const unsigned base = ~(unsigned)p0;

    int cur = 0;
    float cx = sxyz[0], cy = sxyz[1], cz = sxyz[2];
    for (int t = 0; t < NPOINT; t++){
        if (tid == 0) sidx[t] = cur;
        const f32x2 c2x = f32x2{cx, cx}, c2y = f32x2{cy, cy}, c2z = f32x2{cz, cz};
#pragma unroll
        for (int j = 0; j < 8; j++){
            f32x2 dx = X2[j] - c2x;
            f32x2 dy = Y2[j] - c2y;
            f32x2 dz = Z2[j] - c2z;
            f32x2 d2 = dx*dx + dy*dy + dz*dz;      // contract(off): per-op RNE, numpy order
            M2[j].x = fminf(M2[j].x, d2.x);
            M2[j].y = fminf(M2[j].y, d2.y);
        }
        float tv[8];
#pragma unroll
        for (int j = 0; j < 8; j++) tv[j] = fmaxf(M2[j].x, M2[j].y);
        float t0_ = fmaxf(fmaxf(tv[0], tv[1]), fmaxf(tv[2], tv[3]));
        float t1_ = fmaxf(fmaxf(tv[4], tv[5]), fmaxf(tv[6], tv[7]));
        const float mt = fmaxf(t0_, t1_);
        unsigned jpos = 0;
#pragma unroll
        for (int j = 7; j >= 0; j--){
            if (M2[j].y == mt) jpos = 2*j + 1;
            if (M2[j].x == mt) jpos = 2*j;
        }
        const unsigned lo = base - jpos;
        const unsigned mtu = __float_as_uint(mt);
        unsigned vm = dpp_umax_wave(mtu);
        const unsigned wvu = __builtin_amdgcn_readlane(vm, 63);
        unsigned long long cand = __ballot(mtu == wvu);
        const int fl = __ffsll((long long)cand) - 1;
        const unsigned wlo = __builtin_amdgcn_readlane(lo, fl);
        if ((tid & 63) == 0)
            wslots[(t & 1) * 8 + (tid >> 6)] = (((unsigned long long)wvu) << 32) | wlo;
        __syncthreads();
        const ulonglong2* sp = (const ulonglong2*)(wslots + (t & 1) * 8);
        ulonglong2 ka = sp[0], kb = sp[1], kc = sp[2], kd = sp[3];
        unsigned long long ma = (ka.y > ka.x) ? ka.y : ka.x;
        unsigned long long mb = (kb.y > kb.x) ? kb.y : kb.x;
        unsigned long long mc = (kc.y > kc.x) ? kc.y : kc.x;
        unsigned long long md = (kd.y > kd.x) ? kd.y : kd.x;
        unsigned long long mab = (mb > ma) ? mb : ma;
        unsigned long long mcd = (md > mc) ? md : mc;
        unsigned long long win = (mcd > mab) ? mcd : mab;
        cur = (int)(~((unsigned)win));
        const float4 cc4 = sxyz4[cur];
        cx = cc4.x; cy = cc4.y; cz = cc4.z;
    }
    __syncthreads();
#pragma unroll
    for (int q = 0; q < 2; q++){
        const int i = (q << 9) + tid;
        const int idx = sidx[i];
        fps_idx[b * NPOINT + i] = idx;
        const float4 c4 = sxyz4[idx];
        float* oxp = out_xyz + b * 3 * NPOINT;
        oxp[i]            = c4.x;
        oxp[NPOINT + i]   = c4.y;
        oxp[2*NPOINT + i] = c4.z;
    }
}

// ---------- 2) ball query: one wave per (b,s), EXACT arithmetic ----------
__global__ __launch_bounds__(256) void ballquery_kernel(const float* __restrict__ xyz,
                                                        const int* __restrict__ fps_idx, int* __restrict__ gidx){
    const int w = (blockIdx.x << 2) + (threadIdx.x >> 6);
    const int lane = threadIdx.x & 63;
    const int b = w >> 10, s = w & 1023;
    const float* px = xyz + (size_t)b * 3 * NPTS;
    const int ci = fps_idx[b * NPOINT + s];
    const float cx = px[ci], cy = px[NPTS+ci], cz = px[2*NPTS+ci];
    int* gout = gidx + (size_t)b * LCOLS + s * NSAMP;
    int have = 0, first_p = 0; bool got = false;
    for (int c0 = 0; c0 < NPTS; c0 += 64){
        int p = c0 + lane;
        float dx = sub_rn(px[p], cx), dy = sub_rn(px[NPTS+p], cy), dz = sub_rn(px[2*NPTS+p], cz);
        float d2 = add_rn(add_rn(mul_rn(dx,dx), mul_rn(dy,dy)), mul_rn(dz,dz));
        bool in = (d2 <= 0.01f);
        unsigned long long m = __ballot(in);
        if (m && !got){ first_p = c0 + __ffsll(m) - 1; got = true; }
        if (in){
            int pos = have + __popcll(m & ((1ull << lane) - 1ull));
            if (pos < NSAMP) gout[pos] = p;
        }
        have += __popcll(m);
        if (have >= NSAMP) break;
    }
    for (int pos = have + lane; pos < NSAMP; pos += 64) gout[pos] = first_p;
}

// ---------- 3) MFMA conv0 + stats (gather-staged, K=96 channel-permuted) ----------
__global__ __launch_bounds__(256) void mfma_mm0_kernel(
        const float* __restrict__ xyz, const float* __restrict__ nx,
        const uint16_t* __restrict__ ptsT, const int* __restrict__ gidx,
        const uint16_t* __restrict__ wpack, const float* __restrict__ bias,
        uint16_t* __restrict__ xout, float* __restrict__ ssc){
    __shared__ __align__(16) uint16_t sB[12 * 256 * 8];   // 48KB
    __shared__ __align__(16) uint16_t sA[12 * 64 * 8];    // 12KB
    __shared__ float sb_[64];
    __shared__ float sred_s[4][64], sred_ss[4][64];
    const int tid = threadIdx.x;
    const int b = blockIdx.x >> 7;
    const int n0 = (blockIdx.x & 127) << 8;

    if (tid < 64) sb_[tid] = bias[tid];
    for (int i = tid; i < 12*64; i += 256) *(u16x8*)&sA[i*8] = *(const u16x8*)&wpack[i*8];
    __syncthreads();
    {   // stage: thread = column; channels permuted (pts 0..63, xyz 64..66, pad 67..95)
        const int ls = n0 + tid;
        const int s = ls >> 5;
        const int g = gidx[(size_t)b * LCOLS + ls];
        const float* px = xyz + (size_t)b * 3 * NPTS;
        float f0 = sub_rn(px[g],        nx[b*3*NPOINT + s]);
        float f1 = sub_rn(px[NPTS+g],   nx[b*3*NPOINT + NPOINT + s]);
        float f2 = sub_rn(px[2*NPTS+g], nx[b*3*NPOINT + 2*NPOINT + s]);
        const u16x8* pr = (const u16x8*)(ptsT + ((size_t)b * NPTS + (size_t)g) * 64);
#pragma unroll
        for (int kc = 0; kc < 8; kc++) *(u16x8*)&sB[(kc*256 + tid)*8] = pr[kc];
        u16x8 xrow; xrow[0] = f2bf(f0); xrow[1] = f2bf(f1); xrow[2] = f2bf(f2);
        xrow[3] = 0; xrow[4] = 0; xrow[5] = 0; xrow[6] = 0; xrow[7] = 0;
        *(u16x8*)&sB[(8*256 + tid)*8] = xrow;
        u16x8 zr; zr[0]=0;zr[1]=0;zr[2]=0;zr[3]=0;zr[4]=0;zr[5]=0;zr[6]=0;zr[7]=0;
#pragma unroll
        for (int kc = 9; kc < 12; kc++) *(u16x8*)&sB[(kc*256 + tid)*8] = zr;
    }
    __syncthreads();

    const int lane = tid & 63, w = tid >> 6;
    const int lhi = lane >> 4, llo = lane & 15;
    fx4 acc[4][4];
#pragma unroll
    for (int mt = 0; mt < 4; mt++)
#pragma unroll
        for (int nt = 0; nt < 4; nt++) acc[mt][nt] = fx4{0.f,0.f,0.f,0.f};

#pragma unroll
    for (int kk = 0; kk < 3; kk++){
        bf16x8 bfrag[4];
#pragma unroll
        for (int nt = 0; nt < 4; nt++){
            int n = w * 64 + nt * 16 + llo;
            bfrag[nt] = *(const bf16x8*)&sB[((kk*4 + lhi) * 256 + n) * 8];
        }
#pragma unroll
        for (int mt = 0; mt < 4; mt++){
            bf16x8 afrag = *(const bf16x8*)&sA[((kk*4 + lhi) * 64 + mt*16 + llo) * 8];
#pragma unroll
            for (int nt = 0; nt < 4; nt++)
                acc[mt][nt] = __builtin_amdgcn_mfma_f32_16x16x32_bf16(afrag, bfrag[nt], acc[mt][nt], 0, 0, 0);
        }
    }
#pragma unroll
    for (int mt = 0; mt < 4; mt++){
#pragma unroll
        for (int j = 0; j < 4; j++){
            const int ch = mt*16 + lhi*4 + j;
            const float bv = sb_[ch];
            float a0 = acc[mt][0][j] + bv, a1 = acc[mt][1][j] + bv;
            float a2 = acc[mt][2][j] + bv, a3 = acc[mt][3][j] + bv;
            uint16_t* op = xout + (size_t)b * 64 * LCOLS + (size_t)ch * LCOLS + n0 + w*64 + llo;
            op[0]  = f2bf(a0); op[16] = f2bf(a1); op[32] = f2bf(a2); op[48] = f2bf(a3);
            float s  = (a0 + a1) + (a2 + a3);
            float ss = fmaf(a0, a0, fmaf(a1, a1, fmaf(a2, a2, a3*a3)));
#pragma unroll
            for (int off = 1; off < 16; off <<= 1){ s += __shfl_xor(s, off); ss += __shfl_xor(ss, off); }
            if (llo == 0){ sred_s[w][ch] = s; sred_ss[w][ch] = ss; }
        }
    }
    __syncthreads();
    if (tid < 64){
        float s  = sred_s[0][tid]  + sred_s[1][tid]  + sred_s[2][tid]  + sred_s[3][tid];
        float ss = sred_ss[0][tid] + sred_ss[1][tid] + sred_ss[2][tid] + sred_ss[3][tid];
        float* sbck = ssc + (blockIdx.x & (NBUCK-1)) * 256;
        atomicAdd(&sbck[tid], s);
        atomicAdd(&sbck[128 + tid], ss);
    }
}

// ---------- 4) MFMA conv+stats, stats-only (layer1 stats from t0) ----------
__global__ __launch_bounds__(256) void mfma_stats1_kernel(
        const uint16_t* __restrict__ xin, const uint16_t* __restrict__ wpack,
        const float* __restrict__ bias,
        const float* __restrict__ pssc, const float* __restrict__ pg, const float* __restrict__ pbeta,
        float* __restrict__ ssc){
    __shared__ __align__(16) uint16_t sB[8 * 256 * 8];       // 32KB
    __shared__ __align__(16) uint16_t sA[8 * 64 * 8];        // 8KB
    __shared__ float sa_[64], sc_[64], sb_[64];
    __shared__ float sred_s[4][64], sred_ss[4][64];
    const int tid = threadIdx.x;
    const int b = blockIdx.x >> 7;
    const int n0 = (blockIdx.x & 127) << 8;

    if (tid < 64){
        float s = 0.f, ss = 0.f;
#pragma unroll 4
        for (int k = 0; k < NBUCK; k++){ s += pssc[k*256 + tid]; ss += pssc[k*256 + 128 + tid]; }
        const float inv = 1.0f / NTOT;
        float mean = s * inv;
        float var  = ss * inv - mean * mean;
        float a = pg[tid] / sqrtf(var + 1e-5f);
        sa_[tid] = a;
        sc_[tid] = fmaf(-mean, a, pbeta[tid]);
        sb_[tid] = bias[tid];
    }
    for (int i = tid; i < 64*8; i += 256) *(u16x8*)&sA[i*8] = *(const u16x8*)&wpack[i*8];
    __syncthreads();
    {
        const uint16_t* xp = xin + (size_t)b * 64 * LCOLS + (n0 + tid);
#pragma unroll 8
        for (int c = 0; c < 64; c++){
            float v = bf2f(xp[(size_t)c * LCOLS]);
            v = fmaxf(fmaf(sa_[c], v, sc_[c]), 0.0f);
            sB[((c >> 3) * 256 + tid) * 8 + (c & 7)] = f2bf(v);
        }
    }
    __syncthreads();
    const int lane = tid & 63, w = tid >> 6;
    const int lhi = lane >> 4, llo = lane & 15;
    fx4 acc[4][4];
#pragma unroll
    for (int mt = 0; mt < 4; mt++)
#pragma unroll
        for (int nt = 0; nt < 4; nt++) acc[mt][nt] = fx4{0.f,0.f,0.f,0.f};
#pragma unroll
    for (int kk = 0; kk < 2; kk++){
        bf16x8 bfrag[4];
#pragma unroll
        for (int nt = 0; nt < 4; nt++){
            int n = w * 64 + nt * 16 + llo;
            bfrag[nt] = *(const bf16x8*)&sB[((kk*4 + lhi) * 256 + n) * 8];
        }
#pragma unroll
        for (int mt = 0; mt < 4; mt++){
            bf16x8 afrag = *(const bf16x8*)&sA[((kk*4 + lhi) * 64 + mt*16 + llo) * 8];
#pragma unroll
            for (int nt = 0; nt < 4; nt++)
                acc[mt][nt] = __builtin_amdgcn_mfma_f32_16x16x32_bf16(afrag, bfrag[nt], acc[mt][nt], 0, 0, 0);
        }
    }
#pragma unroll
    for (int mt = 0; mt < 4; mt++){
#pragma unroll
        for (int j = 0; j < 4; j++){
            const int ch = mt*16 + lhi*4 + j;
            const float bv = sb_[ch];
            float a0 = acc[mt][0][j] + bv, a1 = acc[mt][1][j] + bv;
            float a2 = acc[mt][2][j] + bv, a3 = acc[mt][3][j] + bv;
            float s  = (a0 + a1) + (a2 + a3);
            float ss = fmaf(a0, a0, fmaf(a1, a1, fmaf(a2, a2, a3*a3)));
#pragma unroll
            for (int off = 1; off < 16; off <<= 1){ s += __shfl_xor(s, off); ss += __shfl_xor(ss, off); }
            if (llo == 0){ sred_s[w][ch] = s; sred_ss[w][ch] = ss; }
        }
    }
    __syncthreads();
    if (tid < 64){
        float s  = sred_s[0][tid]  + sred_s[1][tid]  + sred_s[2][tid]  + sred_s[3][tid];
        float ss = sred_ss[0][tid] + sred_ss[1][tid] + sred_ss[2][tid] + sred_ss[3][tid];
        float* sbck = ssc + (blockIdx.x & (NBUCK-1)) * 256;
        atomicAdd(&sbck[tid], s);
        atomicAdd(&sbck[128 + tid], ss);
    }
}

// ---------- 5) fused layers 1+2: re-stage t0 -> MFMA L1 -> BN1+relu -> LDS -> MFMA L2 -> stats2/max/min ----------
__global__ __launch_bounds__(256) void mfma_mm12_kernel(
        const uint16_t* __restrict__ xin,
        const uint16_t* __restrict__ wpk1, const uint16_t* __restrict__ wpk2,
        const float* __restrict__ b1, const float* __restrict__ b2,
        const float* __restrict__ ssc0, const float* __restrict__ g0, const float* __restrict__ be0,
        const float* __restrict__ ssc1, const float* __restrict__ g1, const float* __restrict__ be1,
        float* __restrict__ ssc2, unsigned* __restrict__ mmax, unsigned* __restrict__ mmin){
    __shared__ __align__(16) uint16_t sB[8 * 256 * 8];       // 32KB : B0 then B1 (aliased)
    __shared__ __align__(16) uint16_t sA1[8 * 64 * 8];       // 8KB
    __shared__ __align__(16) uint16_t sA2[8 * 128 * 8];      // 16KB
    __shared__ float sa0_[64], sc0_[64], sa1_[64], sc1_[64], sb1_[64], sb2_[128];
    __shared__ float sred_s[4][128], sred_ss[4][128], sred_mx[4][128], sred_mn[4][128];
    const int tid = threadIdx.x;
    const int b = blockIdx.x >> 7;
    const int n0 = (blockIdx.x & 127) << 8;

    if (tid < 64){
        float s0 = 0.f, ss0 = 0.f, s1 = 0.f, ss1 = 0.f;
#pragma unroll 4
        for (int k = 0; k < NBUCK; k++){
            s0 += ssc0[k*256 + tid]; ss0 += ssc0[k*256 + 128 + tid];
            s1 += ssc1[k*256 + tid]; ss1 += ssc1[k*256 + 128 + tid];
        }
        const float inv = 1.0f / NTOT;
        float m0 = s0 * inv, v0 = ss0 * inv - m0*m0;
        float a0 = g0[tid] / sqrtf(v0 + 1e-5f);
        sa0_[tid] = a0; sc0_[tid] = fmaf(-m0, a0, be0[tid]);
        float m1 = s1 * inv, v1 = ss1 * inv - m1*m1;
        float a1 = g1[tid] / sqrtf(v1 + 1e-5f);
        sa1_[tid] = a1; sc1_[tid] = fmaf(-m1, a1, be1[tid]);
        sb1_[tid] = b1[tid];
    }
    if (tid < 128) sb2_[tid] = b2[tid];
    for (int i = tid; i < 64*8; i += 256)  *(u16x8*)&sA1[i*8] = *(const u16x8*)&wpk1[i*8];
    for (int i = tid; i < 128*8; i += 256) *(u16x8*)&sA2[i*8] = *(const u16x8*)&wpk2[i*8];
    __syncthreads();
    {   // stage B0 = relu(affine0(t0))
        const uint16_t* xp = xin + (size_t)b * 64 * LCOLS + (n0 + tid);
#pragma unroll 8
        for (int c = 0; c < 64; c++){
            float v = bf2f(xp[(size_t)c * LCOLS]);
            v = fmaxf(fmaf(sa0_[c], v, sc0_[c]), 0.0f);
            sB[((c >> 3) * 256 + tid) * 8 + (c & 7)] = f2bf(v);
        }
    }
    __syncthreads();
    const int lane = tid & 63, w = tid >> 6;
    const int lhi = lane >> 4, llo = lane & 15;

    // ---- layer1 MFMA ----
    fx4 acc1[4][4];
#pragma unroll
    for (int mt = 0; mt < 4; mt++)
#pragma unroll
        for (int nt = 0; nt < 4; nt++) acc1[mt][nt] = fx4{0.f,0.f,0.f,0.f};
#pragma unroll
    for (int kk = 0; kk < 2; kk++){
        bf16x8 bfrag[4];
#pragma unroll
        for (int nt = 0; nt < 4; nt++){
            int n = w * 64 + nt * 16 + llo;
            bfrag[nt] = *(const bf16x8*)&sB[((kk*4 + lhi) * 256 + n) * 8];
        }
#pragma unroll
        for (int mt = 0; mt < 4; mt++){
            bf16x8 afrag = *(const bf16x8*)&sA1[((kk*4 + lhi) * 64 + mt*16 + llo) * 8];
#pragma unroll
            for (int nt = 0; nt < 4; nt++)
                acc1[mt][nt] = __builtin_amdgcn_mfma_f32_16x16x32_bf16(afrag, bfrag[nt], acc1[mt][nt], 0, 0, 0);
        }
    }
    __syncthreads();   // all B0 reads complete before aliasing as B1

    // ---- z = relu(affine1(conv1+b1)) -> write into B-fragment layout ----
#pragma unroll
    for (int mt = 0; mt < 4; mt++){
#pragma unroll
        for (int j = 0; j < 4; j++){
            const int ch = mt*16 + lhi*4 + j;
            const float bv = sb1_[ch], av = sa1_[ch], cv = sc1_[ch];
#pragma unroll
            for (int nt = 0; nt < 4; nt++){
                float z = fmaxf(fmaf(av, acc1[mt][nt][j] + bv, cv), 0.0f);
                int n = w*64 + nt*16 + llo;
                sB[((ch >> 3) * 256 + n) * 8 + (ch & 7)] = f2bf(z);
            }
        }
    }
    __syncthreads();

    // ---- layer2 MFMA (COUT=128) ----
    fx4 acc2[8][4];
#pragma unroll
    for (int mt = 0; mt < 8; mt++)
#pragma unroll
        for (int nt = 0; nt < 4; nt++) acc2[mt][nt] = fx4{0.f,0.f,0.f,0.f};
#pragma unroll
    for (int kk = 0; kk < 2; kk++){
        bf16x8 bfrag[4];
#pragma unroll
        for (int nt = 0; nt < 4; nt++){
            int n = w * 64 + nt * 16 + llo;
            bfrag[nt] = *(const bf16x8*)&sB[((kk*4 + lhi) * 256 + n) * 8];
        }
#pragma unroll
        for (int mt = 0; mt < 8; mt++){
            bf16x8 afrag = *(const bf16x8*)&sA2[((kk*4 + lhi) * 128 + mt*16 + llo) * 8];
#pragma unroll
            for (int nt = 0; nt < 4; nt++)
                acc2[mt][nt] = __builtin_amdgcn_mfma_f32_16x16x32_bf16(afrag, bfrag[nt], acc2[mt][nt], 0, 0, 0);
        }
    }
    // ---- stats2 + max/min (no global tensor write) ----
#pragma unroll
    for (int mt = 0; mt < 8; mt++){
#pragma unroll
        for (int j = 0; j < 4; j++){
            const int ch = mt*16 + lhi*4 + j;
            const float bv = sb2_[ch];
            float a0 = acc2[mt][0][j] + bv, a1 = acc2[mt][1][j] + bv;
            float a2 = acc2[mt][2][j] + bv, a3 = acc2[mt][3][j] + bv;
            float s  = (a0 + a1) + (a2 + a3);
            float ss = fmaf(a0, a0, fmaf(a1, a1, fmaf(a2, a2, a3*a3)));
            float mx = fmaxf(fmaxf(a0, a1), fmaxf(a2, a3));
            float mn = fminf(fminf(a0, a1), fminf(a2, a3));
#pragma unroll
            for (int off = 1; off < 16; off <<= 1){
                s += __shfl_xor(s, off); ss += __shfl_xor(ss, off);
                mx = fmaxf(mx, __shfl_xor(mx, off)); mn = fminf(mn, __shfl_xor(mn, off));
            }
            if (llo == 0){ sred_s[w][ch] = s; sred_ss[w][ch] = ss; sred_mx[w][ch] = mx; sred_mn[w][ch] = mn; }
        }
    }
    __syncthreads();
    if (tid < 128){
        float s  = sred_s[0][tid]  + sred_s[1][tid]  + sred_s[2][tid]  + sred_s[3][tid];
        float ss = sred_ss[0][tid] + sred_ss[1][tid] + sred_ss[2][tid] + sred_ss[3][tid];
        float mx = fmaxf(fmaxf(sred_mx[0][tid], sred_mx[1][tid]), fmaxf(sred_mx[2][tid], sred_mx[3][tid]));
        float mn = fminf(fminf(sred_mn[0][tid], sred_mn[1][tid]), fminf(sred_mn[2][tid], sred_mn[3][tid]));
        float* sbck = ssc2 + (blockIdx.x & (NBUCK-1)) * 256;
        atomicAdd(&sbck[tid], s);
        atomicAdd(&sbck[128 + tid], ss);
        atomicMax(&mmax[b * 128 + tid], fkey(mx));
        atomicMin(&mmin[b * 128 + tid], fkey(mn));
    }
}

// ---------- 6) finalize: out = relu(a * (a>=0 ? max : min) + c) per (b,ch) ----------
__global__ __launch_bounds__(64) void final_kernel(const float* __restrict__ ssc, const float* __restrict__ g2,
                                                   const float* __restrict__ be2, const unsigned* __restrict__ mmax,
                                                   const unsigned* __restrict__ mmin, float* __restrict__ out){
    const int t = blockIdx.x * 64 + threadIdx.x;   // 0..2047 : b*128+o
    const int o = t & 127;
    float s = 0.f, ss = 0.f;
    for (int k = 0; k < NBUCK; k++){ s += ssc[k*256 + o]; ss += ssc[k*256 + 128 + o]; }
    const float inv = 1.0f / NTOT;
    float mean = s * inv;
    float var  = ss * inv - mean * mean;
    float a = g2[o] / sqrtf(var + 1e-5f);
    float c = fmaf(-mean, a, be2[o]);
    unsigned k = (a >= 0.f) ? mmax[t] : mmin[t];
    float x = funkey(k);
    out[49152 + t] = fmaxf(fmaf(a, x, c), 0.0f);
}

extern "C" void kernel_launch(void* const* d_in, const int* in_sizes, int n_in,
                              void* d_out, int out_size, void* d_ws, size_t ws_size,
                              hipStream_t stream){
    const float* xyz = (const float*)d_in[0];
    const float* pts = (const float*)d_in[1];
    const float* w0  = (const float*)d_in[2];  const float* b0  = (const float*)d_in[3];
    const float* g0  = (const float*)d_in[4];  const float* be0 = (const float*)d_in[5];
    const float* w1  = (const float*)d_in[6];  const float* b1  = (const float*)d_in[7];
    const float* g1  = (const float*)d_in[8];  const float* be1 = (const float*)d_in[9];
    const float* w2  = (const float*)d_in[10]; const float* b2  = (const float*)d_in[11];
    const float* g2  = (const float*)d_in[12]; const float* be2 = (const float*)d_in[13];
    float* out = (float*)d_out;
    char* ws = (char*)d_ws;

    int*      fps_idx = (int*)(ws + OFF_FPS);
    int*      gidx    = (int*)(ws + OFF_GIDX);
    float*    ssc0    = (float*)(ws + OFF_SSC);
    float*    ssc1    = ssc0 + NBUCK*256;
    float*    ssc2    = ssc1 + NBUCK*256;
    unsigned* mmax    = (unsigned*)(ws + OFF_MM);
    unsigned* mmin    = mmax + 2048;
    uint16_t* wpk0    = (uint16_t*)(ws + OFF_WPK0);
    uint16_t* wpk1    = (uint16_t*)(ws + OFF_WPK1);
    uint16_t* wpk2    = (uint16_t*)(ws + OFF_WPK2);
    uint16_t* t0      = (uint16_t*)(ws + OFF_T0);
    uint16_t* ptsT    = (uint16_t*)(ws + OFF_PTST);

    hipMemsetAsync(ws + OFF_SSC, 0, 3 * NBUCK * 256 * 4, stream);
    hipMemsetAsync(ws + OFF_MM, 0x00, 8192, stream);
    hipMemsetAsync(ws + OFF_MM + 8192, 0xFF, 8192, stream);

    fps_fused_kernel<<<2080, 512, 0, stream>>>(xyz, fps_idx, out, pts, ptsT,
                                               w0, w1, w2, wpk0, wpk1, wpk2);
    ballquery_kernel<<<4096, 256, 0, stream>>>(xyz, fps_idx, gidx);

    mfma_mm0_kernel<<<2048, 256, 0, stream>>>(xyz, out, ptsT, gidx, wpk0, b0, t0, ssc0);

    mfma_stats1_kernel<<<2048, 256, 0, stream>>>(t0, wpk1, b1, ssc0, g0, be0, ssc1);

    mfma_mm12_kernel<<<2048, 256, 0, stream>>>(t0, wpk1, wpk2, b1, b2,
                                               ssc0, g0, be0, ssc1, g1, be1,
                                               ssc2, mmax, mmin);

    final_kernel<<<32, 64, 0, stream>>>(ssc2, g2, be2, mmax, mmin, out);
}

// Round 16
// 1148.522 us; speedup vs baseline: 1.0646x; 1.0646x over previous
//
#include <hip/hip_runtime.h>
#include <stdint.h>
#include <limits.h>

// ---------- exact-rounding helpers (match numpy op order; used in selection kernels) ----------
__device__ inline float mul_rn(float a, float b){ float r; asm("v_mul_f32 %0, %1, %2" : "=v"(r) : "v"(a), "v"(b)); return r; }
__device__ inline float add_rn(float a, float b){ float r; asm("v_add_f32 %0, %1, %2" : "=v"(r) : "v"(a), "v"(b)); return r; }
__device__ inline float sub_rn(float a, float b){ float r; asm("v_sub_f32 %0, %1, %2" : "=v"(r) : "v"(a), "v"(b)); return r; }

typedef uint16_t u16x8 __attribute__((ext_vector_type(8)));
typedef float    f32x2 __attribute__((ext_vector_type(2)));
typedef short    bf16x8 __attribute__((ext_vector_type(8)));
typedef float    fx4 __attribute__((ext_vector_type(4)));

__device__ inline float bf2f(uint16_t u){ return __uint_as_float(((uint32_t)u) << 16); }
__device__ inline uint16_t f2bf(float f){
    uint32_t u = __float_as_uint(f);
    u += 0x7fffu + ((u >> 16) & 1u);   // RNE
    return (uint16_t)(u >> 16);
}
__device__ inline unsigned fkey(float f){
    unsigned u = __float_as_uint(f);
    return (u & 0x80000000u) ? ~u : (u | 0x80000000u);
}
__device__ inline float funkey(unsigned k){
    unsigned u = (k & 0x80000000u) ? (k ^ 0x80000000u) : ~k;
    return __uint_as_float(u);
}

// full-wave u32 max via DPP builtins (compiler inserts hazard waits). Valid in lane 63.
__device__ inline unsigned dpp_umax_wave(unsigned v){
    unsigned t;
    t = (unsigned)__builtin_amdgcn_update_dpp((int)v, (int)v, 0x111, 0xf, 0xf, false); v = v > t ? v : t;
    t = (unsigned)__builtin_amdgcn_update_dpp((int)v, (int)v, 0x112, 0xf, 0xf, false); v = v > t ? v : t;
    t = (unsigned)__builtin_amdgcn_update_dpp((int)v, (int)v, 0x114, 0xf, 0xf, false); v = v > t ? v : t;
    t = (unsigned)__builtin_amdgcn_update_dpp((int)v, (int)v, 0x118, 0xf, 0xf, false); v = v > t ? v : t;
    t = (unsigned)__builtin_amdgcn_update_dpp((int)v, (int)v, 0x142, 0xf, 0xf, false); v = v > t ? v : t;
    t = (unsigned)__builtin_amdgcn_update_dpp((int)v, (int)v, 0x143, 0xf, 0xf, false); v = v > t ? v : t;
    return v;
}

#define NPTS   8192
#define NBATCH 16
#define NPOINT 1024
#define NSAMP  32
#define LCOLS  32768          // NPOINT*NSAMP
#define NTOT   524288.0f      // 16*32768
#define NBUCK  32

// ---------- workspace layout (bytes) ----------
#define OFF_FPS   0u               // 16*1024*4 = 65536
#define OFF_GIDX  65536u           // 16*1024*32*4 = 2097152
#define OFF_SSC   2162688u         // 3 layers * 32 buckets * 256 f32 = 98304
#define OFF_MM    2263040u         // mmax 2048 u32 ; mmin 2048 u32 = 16384
#define OFF_WPK0  2279424u         // 6144 u16 = 12288 (layer0, K=96 permuted)
#define OFF_WPK1  2291712u         // 4096 u16 = 8192
#define OFF_WPK2  2299904u         // 8192 u16 = 16384 (end 2316288)
#define OFF_T0    4194304u         // 67108864 (raw conv0 out, bf16)
#define OFF_PTST  138412032u       // 16777216 (end 155189248)

// ---------- 1) FUSED (512 thr/block): fps (0..15) + pts transpose (16..2063) + prep (2064..2079) ----------
__global__ __launch_bounds__(512) void fps_fused_kernel(const float* __restrict__ xyz,
        int* __restrict__ fps_idx, float* __restrict__ out_xyz,
        const float* __restrict__ pts, uint16_t* __restrict__ ptsT,
        const float* __restrict__ w0, const float* __restrict__ w1, const float* __restrict__ w2,
        uint16_t* __restrict__ wpk0, uint16_t* __restrict__ wpk1, uint16_t* __restrict__ wpk2){
#pragma clang fp contract(off)
    __shared__ __align__(16) float smem[33824];   // sxyz4 32768 + wslots 32 + sidx 1024
    const int bid = blockIdx.x, tid = threadIdx.x;

    if (bid >= 2064){                      // ---- prep path: pack weights for MFMA ----
        int t = (bid - 2064) * 512 + tid;  // 0..8191
        if (t < 64*96){                    // layer0: channel-permuted K=96 (pts 0..63, xyz 64..66, pad)
            int o = t / 96, cp = t % 96;
            uint16_t v = 0;
            if (cp < 64)      v = f2bf(w0[o*67 + (cp + 3)]);   // pts channel
            else if (cp < 67) v = f2bf(w0[o*67 + (cp - 64)]);  // xyz channel
            wpk0[((cp>>3)*64 + o)*8 + (cp&7)] = v;
        }
        if (t < 64*64){ int o = t >> 6, c = t & 63; wpk1[((c>>3)*64  + o)*8 + (c&7)] = f2bf(w1[t]); }
        if (t < 128*64){ int o = t >> 6, c = t & 63; wpk2[((c>>3)*128 + o)*8 + (c&7)] = f2bf(w2[t]); }
        return;
    }
    if (bid >= 16){                        // ---- transpose path: (B,64,N)f32 -> (B,N,64)bf16 ----
        float (*tile)[65] = (float(*)[65])smem;
        const int tb = bid - 16;
        const int bt = tb >> 7, n0 = (tb & 127) << 6;
        const int tn = tid & 63, tg = tid >> 6;             // tg 0..7, 8 c's each
        const float* src = pts + (size_t)bt * 64 * NPTS + n0;
#pragma unroll
        for (int i = 0; i < 8; i++){ int c = tg*8 + i; tile[c][tn] = src[(size_t)c * NPTS + tn]; }
        __syncthreads();
        uint16_t* dst = ptsT + ((size_t)bt * NPTS + n0) * 64;
#pragma unroll
        for (int i = 0; i < 8; i++){ int n = tg*8 + i; dst[(size_t)n * 64 + tn] = f2bf(tile[tn][n]); }
        return;
    }

    // ---- fps path: 512 threads (2 waves/SIMD), 16 points/thread, EXACT numpy-order arithmetic ----
    float* sxyz = smem;
    float4* sxyz4 = (float4*)smem;
    unsigned long long* wslots = (unsigned long long*)(smem + 32768);   // [2*8]
    int* sidx = (int*)(smem + 32800);                                   // [1024]
    const int b = bid;
    const float* px = xyz + (size_t)b * 3 * NPTS;
    for (int i = tid; i < NPTS; i += 512)
        sxyz4[i] = float4{px[i], px[NPTS + i], px[2*NPTS + i], 0.f};
    __syncthreads();

    const int p0 = tid << 4;
    const float4* rp = sxyz4 + p0;
    f32x2 X2[8], Y2[8], Z2[8], M2[8];
#pragma unroll
    for (int j = 0; j < 8; j++){
        float4 qa = rp[2*j], qb = rp[2*j + 1];
        X2[j] = f32x2{qa.x, qb.x};
        Y2[j] = f32x2{qa.y, qb.y};
        Z2[j] = f32x2{qa.z, qb.z};
        M2[j] = f32x2{1e10f, 1e10f};
    }
    const unsigned base = ~(unsigned)p0;

    int cur = 0;
    float cx = sxyz[0], cy = sxyz[1], cz = sxyz[2];
    for (int t = 0; t < NPOINT; t++){
        if (tid == 0) sidx[t] = cur;
        const f32x2 c2x = f32x2{cx, cx}, c2y = f32x2{cy, cy}, c2z = f32x2{cz, cz};
#pragma unroll
        for (int j = 0; j < 8; j++){
            f32x2 dx = X2[j] - c2x;
            f32x2 dy = Y2[j] - c2y;
            f32x2 dz = Z2[j] - c2z;
            f32x2 d2 = dx*dx + dy*dy + dz*dz;      // contract(off): per-op RNE, numpy order
            M2[j].x = fminf(M2[j].x, d2.x);
            M2[j].y = fminf(M2[j].y, d2.y);
        }
        float tv[8];
#pragma unroll
        for (int j = 0; j < 8; j++) tv[j] = fmaxf(M2[j].x, M2[j].y);
        float t0_ = fmaxf(fmaxf(tv[0], tv[1]), fmaxf(tv[2], tv[3]));
        float t1_ = fmaxf(fmaxf(tv[4], tv[5]), fmaxf(tv[6], tv[7]));
        const float mt = fmaxf(t0_, t1_);
        unsigned jpos = 0;
#pragma unroll
        for (int j = 7; j >= 0; j--){
            if (M2[j].y == mt) jpos = 2*j + 1;
            if (M2[j].x == mt) jpos = 2*j;
        }
        const unsigned lo = base - jpos;
        const unsigned mtu = __float_as_uint(mt);
        unsigned vm = dpp_umax_wave(mtu);
        const unsigned wvu = __builtin_amdgcn_readlane(vm, 63);
        unsigned long long cand = __ballot(mtu == wvu);
        const int fl = __ffsll((long long)cand) - 1;
        const unsigned wlo = __builtin_amdgcn_readlane(lo, fl);
        if ((tid & 63) == 0)
            wslots[(t & 1) * 8 + (tid >> 6)] = (((unsigned long long)wvu) << 32) | wlo;
        __syncthreads();
        const ulonglong2* sp = (const ulonglong2*)(wslots + (t & 1) * 8);
        ulonglong2 ka = sp[0], kb = sp[1], kc = sp[2], kd = sp[3];
        unsigned long long ma = (ka.y > ka.x) ? ka.y : ka.x;
        unsigned long long mb = (kb.y > kb.x) ? kb.y : kb.x;
        unsigned long long mc = (kc.y > kc.x) ? kc.y : kc.x;
        unsigned long long md = (kd.y > kd.x) ? kd.y : kd.x;
        unsigned long long mab = (mb > ma) ? mb : ma;
        unsigned long long mcd = (md > mc) ? md : mc;
        unsigned long long win = (mcd > mab) ? mcd : mab;
        cur = (int)(~((unsigned)win));
        const float4 cc4 = sxyz4[cur];
        cx = cc4.x; cy = cc4.y; cz = cc4.z;
    }
    __syncthreads();
#pragma unroll
    for (int q = 0; q < 2; q++){
        const int i = (q << 9) + tid;
        const int idx = sidx[i];
        fps_idx[b * NPOINT + i] = idx;
        const float4 c4 = sxyz4[idx];
        float* oxp = out_xyz + b * 3 * NPOINT;
        oxp[i]            = c4.x;
        oxp[NPOINT + i]   = c4.y;
        oxp[2*NPOINT + i] = c4.z;
    }
}

// ---------- 2) ball query: one wave per (b,s); NO early-exit (enables load pipelining) ----------
// In-radius expectation ~34 of 8192 -> break fired at ~94% of scan anyway; removing it
// breaks the load->ballot->branch serial chain so chunk loads pipeline across iterations.
__global__ __launch_bounds__(256) void ballquery_kernel(const float* __restrict__ xyz,
                                                        const int* __restrict__ fps_idx, int* __restrict__ gidx){
    const int w = (blockIdx.x << 2) + (threadIdx.x >> 6);
    const int lane = threadIdx.x & 63;
    const int b = w >> 10, s = w & 1023;
    const float* px = xyz + (size_t)b * 3 * NPTS;
    const int ci = fps_idx[b * NPOINT + s];
    const float cx = px[ci], cy = px[NPTS+ci], cz = px[2*NPTS+ci];
    int* gout = gidx + (size_t)b * LCOLS + s * NSAMP;
    const unsigned long long lmask = (1ull << lane) - 1ull;
    int have = 0, first_p = 0; bool got = false;
    for (int c0 = 0; c0 < NPTS; c0 += 128){
        const int pA = c0 + lane, pB = c0 + 64 + lane;
        // issue all 6 loads up front (no control dependence on this iteration's ballot)
        const float xA = px[pA], yA = px[NPTS+pA], zA = px[2*NPTS+pA];
        const float xB = px[pB], yB = px[NPTS+pB], zB = px[2*NPTS+pB];
        {
            float dx = sub_rn(xA, cx), dy = sub_rn(yA, cy), dz = sub_rn(zA, cz);
            float d2 = add_rn(add_rn(mul_rn(dx,dx), mul_rn(dy,dy)), mul_rn(dz,dz));
            bool in = (d2 <= 0.01f);
            unsigned long long m = __ballot(in);
            if (m && !got){ first_p = c0 + __ffsll((long long)m) - 1; got = true; }
            if (in){
                int pos = have + __popcll(m & lmask);
                if (pos < NSAMP) gout[pos] = pA;
            }
            have += __popcll(m);
        }
        {
            float dx = sub_rn(xB, cx), dy = sub_rn(yB, cy), dz = sub_rn(zB, cz);
            float d2 = add_rn(add_rn(mul_rn(dx,dx), mul_rn(dy,dy)), mul_rn(dz,dz));
            bool in = (d2 <= 0.01f);
            unsigned long long m = __ballot(in);
            if (m && !got){ first_p = c0 + 64 + __ffsll((long long)m) - 1; got = true; }
            if (in){
                int pos = have + __popcll(m & lmask);
                if (pos < NSAMP) gout[pos] = pB;
            }
            have += __popcll(m);
        }
    }
    for (int pos = have + lane; pos < NSAMP; pos += 64) gout[pos] = first_p;
}

// ---------- 3) MFMA conv0 + stats (gather-staged, K=96 channel-permuted) ----------
__global__ __launch_bounds__(256) void mfma_mm0_kernel(
        const float* __restrict__ xyz, const float* __restrict__ nx,
        const uint16_t* __restrict__ ptsT, const int* __restrict__ gidx,
        const uint16_t* __restrict__ wpack, const float* __restrict__ bias,
        uint16_t* __restrict__ xout, float* __restrict__ ssc){
    __shared__ __align__(16) uint16_t sB[12 * 256 * 8];   // 48KB
    __shared__ __align__(16) uint16_t sA[12 * 64 * 8];    // 12KB
    __shared__ float sb_[64];
    __shared__ float sred_s[4][64], sred_ss[4][64];
    const int tid = threadIdx.x;
    const int b = blockIdx.x >> 7;
    const int n0 = (blockIdx.x & 127) << 8;

    if (tid < 64) sb_[tid] = bias[tid];
    for (int i = tid; i < 12*64; i += 256) *(u16x8*)&sA[i*8] = *(const u16x8*)&wpack[i*8];
    __syncthreads();
    {   // stage: thread = column; channels permuted (pts 0..63, xyz 64..66, pad 67..95)
        const int ls = n0 + tid;
        const int s = ls >> 5;
        const int g = gidx[(size_t)b * LCOLS + ls];
        const float* px = xyz + (size_t)b * 3 * NPTS;
        float f0 = sub_rn(px[g],        nx[b*3*NPOINT + s]);
        float f1 = sub_rn(px[NPTS+g],   nx[b*3*NPOINT + NPOINT + s]);
        float f2 = sub_rn(px[2*NPTS+g], nx[b*3*NPOINT + 2*NPOINT + s]);
        const u16x8* pr = (const u16x8*)(ptsT + ((size_t)b * NPTS + (size_t)g) * 64);
#pragma unroll
        for (int kc = 0; kc < 8; kc++) *(u16x8*)&sB[(kc*256 + tid)*8] = pr[kc];
        u16x8 xrow; xrow[0] = f2bf(f0); xrow[1] = f2bf(f1); xrow[2] = f2bf(f2);
        xrow[3] = 0; xrow[4] = 0; xrow[5] = 0; xrow[6] = 0; xrow[7] = 0;
        *(u16x8*)&sB[(8*256 + tid)*8] = xrow;
        u16x8 zr; zr[0]=0;zr[1]=0;zr[2]=0;zr[3]=0;zr[4]=0;zr[5]=0;zr[6]=0;zr[7]=0;
#pragma unroll
        for (int kc = 9; kc < 12; kc++) *(u16x8*)&sB[(kc*256 + tid)*8] = zr;
    }
    __syncthreads();

    const int lane = tid & 63, w = tid >> 6;
    const int lhi = lane >> 4, llo = lane & 15;
    fx4 acc[4][4];
#pragma unroll
    for (int mt = 0; mt < 4; mt++)
#pragma unroll
        for (int nt = 0; nt < 4; nt++) acc[mt][nt] = fx4{0.f,0.f,0.f,0.f};

#pragma unroll
    for (int kk = 0; kk < 3; kk++){
        bf16x8 bfrag[4];
#pragma unroll
        for (int nt = 0; nt < 4; nt++){
            int n = w * 64 + nt * 16 + llo;
            bfrag[nt] = *(const bf16x8*)&sB[((kk*4 + lhi) * 256 + n) * 8];
        }
#pragma unroll
        for (int mt = 0; mt < 4; mt++){
            bf16x8 afrag = *(const bf16x8*)&sA[((kk*4 + lhi) * 64 + mt*16 + llo) * 8];
#pragma unroll
            for (int nt = 0; nt < 4; nt++)
                acc[mt][nt] = __builtin_amdgcn_mfma_f32_16x16x32_bf16(afrag, bfrag[nt], acc[mt][nt], 0, 0, 0);
        }
    }
#pragma unroll
    for (int mt = 0; mt < 4; mt++){
#pragma unroll
        for (int j = 0; j < 4; j++){
            const int ch = mt*16 + lhi*4 + j;
            const float bv = sb_[ch];
            float a0 = acc[mt][0][j] + bv, a1 = acc[mt][1][j] + bv;
            float a2 = acc[mt][2][j] + bv, a3 = acc[mt][3][j] + bv;
            uint16_t* op = xout + (size_t)b * 64 * LCOLS + (size_t)ch * LCOLS + n0 + w*64 + llo;
            op[0]  = f2bf(a0); op[16] = f2bf(a1); op[32] = f2bf(a2); op[48] = f2bf(a3);
            float s  = (a0 + a1) + (a2 + a3);
            float ss = fmaf(a0, a0, fmaf(a1, a1, fmaf(a2, a2, a3*a3)));
#pragma unroll
            for (int off = 1; off < 16; off <<= 1){ s += __shfl_xor(s, off); ss += __shfl_xor(ss, off); }
            if (llo == 0){ sred_s[w][ch] = s; sred_ss[w][ch] = ss; }
        }
    }
    __syncthreads();
    if (tid < 64){
        float s  = sred_s[0][tid]  + sred_s[1][tid]  + sred_s[2][tid]  + sred_s[3][tid];
        float ss = sred_ss[0][tid] + sred_ss[1][tid] + sred_ss[2][tid] + sred_ss[3][tid];
        float* sbck = ssc + (blockIdx.x & (NBUCK-1)) * 256;
        atomicAdd(&sbck[tid], s);
        atomicAdd(&sbck[128 + tid], ss);
    }
}

// ---------- 4) MFMA conv+stats, stats-only (layer1 stats from t0) ----------
__global__ __launch_bounds__(256) void mfma_stats1_kernel(
        const uint16_t* __restrict__ xin, const uint16_t* __restrict__ wpack,
        const float* __restrict__ bias,
        const float* __restrict__ pssc, const float* __restrict__ pg, const float* __restrict__ pbeta,
        float* __restrict__ ssc){
    __shared__ __align__(16) uint16_t sB[8 * 256 * 8];       // 32KB
    __shared__ __align__(16) uint16_t sA[8 * 64 * 8];        // 8KB
    __shared__ float sa_[64], sc_[64], sb_[64];
    __shared__ float sred_s[4][64], sred_ss[4][64];
    const int tid = threadIdx.x;
    const int b = blockIdx.x >> 7;
    const int n0 = (blockIdx.x & 127) << 8;

    if (tid < 64){
        float s = 0.f, ss = 0.f;
#pragma unroll 4
        for (int k = 0; k < NBUCK; k++){ s += pssc[k*256 + tid]; ss += pssc[k*256 + 128 + tid]; }
        const float inv = 1.0f / NTOT;
        float mean = s * inv;
        float var  = ss * inv - mean * mean;
        float a = pg[tid] / sqrtf(var + 1e-5f);
        sa_[tid] = a;
        sc_[tid] = fmaf(-mean, a, pbeta[tid]);
        sb_[tid] = bias[tid];
    }
    for (int i = tid; i < 64*8; i += 256) *(u16x8*)&sA[i*8] = *(const u16x8*)&wpack[i*8];
    __syncthreads();
    {
        const uint16_t* xp = xin + (size_t)b * 64 * LCOLS + (n0 + tid);
#pragma unroll 8
        for (int c = 0; c < 64; c++){
            float v = bf2f(xp[(size_t)c * LCOLS]);
            v = fmaxf(fmaf(sa_[c], v, sc_[c]), 0.0f);
            sB[((c >> 3) * 256 + tid) * 8 + (c & 7)] = f2bf(v);
        }
    }
    __syncthreads();
    const int lane = tid & 63, w = tid >> 6;
    const int lhi = lane >> 4, llo = lane & 15;
    fx4 acc[4][4];
#pragma unroll
    for (int mt = 0; mt < 4; mt++)
#pragma unroll
        for (int nt = 0; nt < 4; nt++) acc[mt][nt] = fx4{0.f,0.f,0.f,0.f};
#pragma unroll
    for (int kk = 0; kk < 2; kk++){
        bf16x8 bfrag[4];
#pragma unroll
        for (int nt = 0; nt < 4; nt++){
            int n = w * 64 + nt * 16 + llo;
            bfrag[nt] = *(const bf16x8*)&sB[((kk*4 + lhi) * 256 + n) * 8];
        }
#pragma unroll
        for (int mt = 0; mt < 4; mt++){
            bf16x8 afrag = *(const bf16x8*)&sA[((kk*4 + lhi) * 64 + mt*16 + llo) * 8];
#pragma unroll
            for (int nt = 0; nt < 4; nt++)
                acc[mt][nt] = __builtin_amdgcn_mfma_f32_16x16x32_bf16(afrag, bfrag[nt], acc[mt][nt], 0, 0, 0);
        }
    }
#pragma unroll
    for (int mt = 0; mt < 4; mt++){
#pragma unroll
        for (int j = 0; j < 4; j++){
            const int ch = mt*16 + lhi*4 + j;
            const float bv = sb_[ch];
            float a0 = acc[mt][0][j] + bv, a1 = acc[mt][1][j] + bv;
            float a2 = acc[mt][2][j] + bv, a3 = acc[mt][3][j] + bv;
            float s  = (a0 + a1) + (a2 + a3);
            float ss = fmaf(a0, a0, fmaf(a1, a1, fmaf(a2, a2, a3*a3)));
#pragma unroll
            for (int off = 1; off < 16; off <<= 1){ s += __shfl_xor(s, off); ss += __shfl_xor(ss, off); }
            if (llo == 0){ sred_s[w][ch] = s; sred_ss[w][ch] = ss; }
        }
    }
    __syncthreads();
    if (tid < 64){
        float s  = sred_s[0][tid]  + sred_s[1][tid]  + sred_s[2][tid]  + sred_s[3][tid];
        float ss = sred_ss[0][tid] + sred_ss[1][tid] + sred_ss[2][tid] + sred_ss[3][tid];
        float* sbck = ssc + (blockIdx.x & (NBUCK-1)) * 256;
        atomicAdd(&sbck[tid], s);
        atomicAdd(&sbck[128 + tid], ss);
    }
}

// ---------- 5) fused layers 1+2: re-stage t0 -> MFMA L1 -> BN1+relu -> LDS -> MFMA L2 -> stats2/max/min ----------
__global__ __launch_bounds__(256) void mfma_mm12_kernel(
        const uint16_t* __restrict__ xin,
        const uint16_t* __restrict__ wpk1, const uint16_t* __restrict__ wpk2,
        const float* __restrict__ b1, const float* __restrict__ b2,
        const float* __restrict__ ssc0, const float* __restrict__ g0, const float* __restrict__ be0,
        const float* __restrict__ ssc1, const float* __restrict__ g1, const float* __restrict__ be1,
        float* __restrict__ ssc2, unsigned* __restrict__ mmax, unsigned* __restrict__ mmin){
    __shared__ __align__(16) uint16_t sB[8 * 256 * 8];       // 32KB : B0 then B1 (aliased)
    __shared__ __align__(16) uint16_t sA1[8 * 64 * 8];       // 8KB
    __shared__ __align__(16) uint16_t sA2[8 * 128 * 8];      // 16KB
    __shared__ float sa0_[64], sc0_[64], sa1_[64], sc1_[64], sb1_[64], sb2_[128];
    __shared__ float sred_s[4][128], sred_ss[4][128], sred_mx[4][128], sred_mn[4][128];
    const int tid = threadIdx.x;
    const int b = blockIdx.x >> 7;
    const int n0 = (blockIdx.x & 127) << 8;

    if (tid < 64){
        float s0 = 0.f, ss0 = 0.f, s1 = 0.f, ss1 = 0.f;
#pragma unroll 4
        for (int k = 0; k < NBUCK; k++){
            s0 += ssc0[k*256 + tid]; ss0 += ssc0[k*256 + 128 + tid];
            s1 += ssc1[k*256 + tid]; ss1 += ssc1[k*256 + 128 + tid];
        }
        const float inv = 1.0f / NTOT;
        float m0 = s0 * inv, v0 = ss0 * inv - m0*m0;
        float a0 = g0[tid] / sqrtf(v0 + 1e-5f);
        sa0_[tid] = a0; sc0_[tid] = fmaf(-m0, a0, be0[tid]);
        float m1 = s1 * inv, v1 = ss1 * inv - m1*m1;
        float a1 = g1[tid] / sqrtf(v1 + 1e-5f);
        sa1_[tid] = a1; sc1_[tid] = fmaf(-m1, a1, be1[tid]);
        sb1_[tid] = b1[tid];
    }
    if (tid < 128) sb2_[tid] = b2[tid];
    for (int i = tid; i < 64*8; i += 256)  *(u16x8*)&sA1[i*8] = *(const u16x8*)&wpk1[i*8];
    for (int i = tid; i < 128*8; i += 256) *(u16x8*)&sA2[i*8] = *(const u16x8*)&wpk2[i*8];
    __syncthreads();
    {   // stage B0 = relu(affine0(t0))
        const uint16_t* xp = xin + (size_t)b * 64 * LCOLS + (n0 + tid);
#pragma unroll 8
        for (int c = 0; c < 64; c++){
            float v = bf2f(xp[(size_t)c * LCOLS]);
            v = fmaxf(fmaf(sa0_[c], v, sc0_[c]), 0.0f);
            sB[((c >> 3) * 256 + tid) * 8 + (c & 7)] = f2bf(v);
        }
    }
    __syncthreads();
    const int lane = tid & 63, w = tid >> 6;
    const int lhi = lane >> 4, llo = lane & 15;

    // ---- layer1 MFMA ----
    fx4 acc1[4][4];
#pragma unroll
    for (int mt = 0; mt < 4; mt++)
#pragma unroll
        for (int nt = 0; nt < 4; nt++) acc1[mt][nt] = fx4{0.f,0.f,0.f,0.f};
#pragma unroll
    for (int kk = 0; kk < 2; kk++){
        bf16x8 bfrag[4];
#pragma unroll
        for (int nt = 0; nt < 4; nt++){
            int n = w * 64 + nt * 16 + llo;
            bfrag[nt] = *(const bf16x8*)&sB[((kk*4 + lhi) * 256 + n) * 8];
        }
#pragma unroll
        for (int mt = 0; mt < 4; mt++){
            bf16x8 afrag = *(const bf16x8*)&sA1[((kk*4 + lhi) * 64 + mt*16 + llo) * 8];
#pragma unroll
            for (int nt = 0; nt < 4; nt++)
                acc1[mt][nt] = __builtin_amdgcn_mfma_f32_16x16x32_bf16(afrag, bfrag[nt], acc1[mt][nt], 0, 0, 0);
        }
    }
    __syncthreads();   // all B0 reads complete before aliasing as B1

    // ---- z = relu(affine1(conv1+b1)) -> write into B-fragment layout ----
#pragma unroll
    for (int mt = 0; mt < 4; mt++){
#pragma unroll
        for (int j = 0; j < 4; j++){
            const int ch = mt*16 + lhi*4 + j;
            const float bv = sb1_[ch], av = sa1_[ch], cv = sc1_[ch];
#pragma unroll
            for (int nt = 0; nt < 4; nt++){
                float z = fmaxf(fmaf(av, acc1[mt][nt][j] + bv, cv), 0.0f);
                int n = w*64 + nt*16 + llo;
                sB[((ch >> 3) * 256 + n) * 8 + (ch & 7)] = f2bf(z);
            }
        }
    }
    __syncthreads();

    // ---- layer2 MFMA (COUT=128) ----
    fx4 acc2[8][4];
#pragma unroll
    for (int mt = 0; mt < 8; mt++)
#pragma unroll
        for (int nt = 0; nt < 4; nt++) acc2[mt][nt] = fx4{0.f,0.f,0.f,0.f};
#pragma unroll
    for (int kk = 0; kk < 2; kk++){
        bf16x8 bfrag[4];
#pragma unroll
        for (int nt = 0; nt < 4; nt++){
            int n = w * 64 + nt * 16 + llo;
            bfrag[nt] = *(const bf16x8*)&sB[((kk*4 + lhi) * 256 + n) * 8];
        }
#pragma unroll
        for (int mt = 0; mt < 8; mt++){
            bf16x8 afrag = *(const bf16x8*)&sA2[((kk*4 + lhi) * 128 + mt*16 + llo) * 8];
#pragma unroll
            for (int nt = 0; nt < 4; nt++)
                acc2[mt][nt] = __builtin_amdgcn_mfma_f32_16x16x32_bf16(afrag, bfrag[nt], acc2[mt][nt], 0, 0, 0);
        }
    }
    // ---- stats2 + max/min (no global tensor write) ----
#pragma unroll
    for (int mt = 0; mt < 8; mt++){
#pragma unroll
        for (int j = 0; j < 4; j++){
            const int ch = mt*16 + lhi*4 + j;
            const float bv = sb2_[ch];
            float a0 = acc2[mt][0][j] + bv, a1 = acc2[mt][1][j] + bv;
            float a2 = acc2[mt][2][j] + bv, a3 = acc2[mt][3][j] + bv;
            float s  = (a0 + a1) + (a2 + a3);
            float ss = fmaf(a0, a0, fmaf(a1, a1, fmaf(a2, a2, a3*a3)));
            float mx = fmaxf(fmaxf(a0, a1), fmaxf(a2, a3));
            float mn = fminf(fminf(a0, a1), fminf(a2, a3));
#pragma unroll
            for (int off = 1; off < 16; off <<= 1){
                s += __shfl_xor(s, off); ss += __shfl_xor(ss, off);
                mx = fmaxf(mx, __shfl_xor(mx, off)); mn = fminf(mn, __shfl_xor(mn, off));
            }
            if (llo == 0){ sred_s[w][ch] = s; sred_ss[w][ch] = ss; sred_mx[w][ch] = mx; sred_mn[w][ch] = mn; }
        }
    }
    __syncthreads();
    if (tid < 128){
        float s  = sred_s[0][tid]  + sred_s[1][tid]  + sred_s[2][tid]  + sred_s[3][tid];
        float ss = sred_ss[0][tid] + sred_ss[1][tid] + sred_ss[2][tid] + sred_ss[3][tid];
        float mx = fmaxf(fmaxf(sred_mx[0][tid], sred_mx[1][tid]), fmaxf(sred_mx[2][tid], sred_mx[3][tid]));
        float mn = fminf(fminf(sred_mn[0][tid], sred_mn[1][tid]), fminf(sred_mn[2][tid], sred_mn[3][tid]));
        float* sbck = ssc2 + (blockIdx.x & (NBUCK-1)) * 256;
        atomicAdd(&sbck[tid], s);
        atomicAdd(&sbck[128 + tid], ss);
        atomicMax(&mmax[b * 128 + tid], fkey(mx));
        atomicMin(&mmin[b * 128 + tid], fkey(mn));
    }
}

// ---------- 6) finalize: out = relu(a * (a>=0 ? max : min) + c) per (b,ch) ----------
__global__ __launch_bounds__(64) void final_kernel(const float* __restrict__ ssc, const float* __restrict__ g2,
                                                   const float* __restrict__ be2, const unsigned* __restrict__ mmax,
                                                   const unsigned* __restrict__ mmin, float* __restrict__ out){
    const int t = blockIdx.x * 64 + threadIdx.x;   // 0..2047 : b*128+o
    const int o = t & 127;
    float s = 0.f, ss = 0.f;
    for (int k = 0; k < NBUCK; k++){ s += ssc[k*256 + o]; ss += ssc[k*256 + 128 + o]; }
    const float inv = 1.0f / NTOT;
    float mean = s * inv;
    float var  = ss * inv - mean * mean;
    float a = g2[o] / sqrtf(var + 1e-5f);
    float c = fmaf(-mean, a, be2[o]);
    unsigned k = (a >= 0.f) ? mmax[t] : mmin[t];
    float x = funkey(k);
    out[49152 + t] = fmaxf(fmaf(a, x, c), 0.0f);
}

extern "C" void kernel_launch(void* const* d_in, const int* in_sizes, int n_in,
                              void* d_out, int out_size, void* d_ws, size_t ws_size,
                              hipStream_t stream){
    const float* xyz = (const float*)d_in[0];
    const float* pts = (const float*)d_in[1];
    const float* w0  = (const float*)d_in[2];  const float* b0  = (const float*)d_in[3];
    const float* g0  = (const float*)d_in[4];  const float* be0 = (const float*)d_in[5];
    const float* w1  = (const float*)d_in[6];  const float* b1  = (const float*)d_in[7];
    const float* g1  = (const float*)d_in[8];  const float* be1 = (const float*)d_in[9];
    const float* w2  = (const float*)d_in[10]; const float* b2  = (const float*)d_in[11];
    const float* g2  = (const float*)d_in[12]; const float* be2 = (const float*)d_in[13];
    float* out = (float*)d_out;
    char* ws = (char*)d_ws;

    int*      fps_idx = (int*)(ws + OFF_FPS);
    int*      gidx    = (int*)(ws + OFF_GIDX);
    float*    ssc0    = (float*)(ws + OFF_SSC);
    float*    ssc1    = ssc0 + NBUCK*256;
    float*    ssc2    = ssc1 + NBUCK*256;
    unsigned* mmax    = (unsigned*)(ws + OFF_MM);
    unsigned* mmin    = mmax + 2048;
    uint16_t* wpk0    = (uint16_t*)(ws + OFF_WPK0);
    uint16_t* wpk1    = (uint16_t*)(ws + OFF_WPK1);
    uint16_t* wpk2    = (uint16_t*)(ws + OFF_WPK2);
    uint16_t* t0      = (uint16_t*)(ws + OFF_T0);
    uint16_t* ptsT    = (uint16_t*)(ws + OFF_PTST);

    hipMemsetAsync(ws + OFF_SSC, 0, 3 * NBUCK * 256 * 4, stream);
    hipMemsetAsync(ws + OFF_MM, 0x00, 8192, stream);
    hipMemsetAsync(ws + OFF_MM + 8192, 0xFF, 8192, stream);

    fps_fused_kernel<<<2080, 512, 0, stream>>>(xyz, fps_idx, out, pts, ptsT,
                                               w0, w1, w2, wpk0, wpk1, wpk2);
    ballquery_kernel<<<4096, 256, 0, stream>>>(xyz, fps_idx, gidx);

    mfma_mm0_kernel<<<2048, 256, 0, stream>>>(xyz, out, ptsT, gidx, wpk0, b0, t0, ssc0);

    mfma_stats1_kernel<<<2048, 256, 0, stream>>>(t0, wpk1, b1, ssc0, g0, be0, ssc1);

    mfma_mm12_kernel<<<2048, 256, 0, stream>>>(t0, wpk1, wpk2, b1, b2,
                                               ssc0, g0, be0, ssc1, g1, be1,
                                               ssc2, mmax, mmin);

    final_kernel<<<32, 64, 0, stream>>>(ssc2, g2, be2, mmax, mmin, out);
}